// Round 6
// baseline (4747.194 us; speedup 1.0000x reference)
//
#include <hip/hip_runtime.h>

#define B_ 128
#define T_ 100
#define D_ 256
#define H_ 512
#define L_ 40000
#define S_ 10

__device__ __forceinline__ float sigm_(float x){ return 1.f/(1.f + __expf(-x)); }
__device__ __forceinline__ float tanh_(float x){ return 1.f - 2.f/(__expf(2.f*x) + 1.f); }

// h exchange element: low 32 = value, high 32 = step tag. 8B atomic => no tearing.
union VT { struct { float val; unsigned tag; } s; unsigned long long u; };

// ---------------- zero h tag-buffer (both parities) ----------------
__global__ void k_zero(unsigned long long* __restrict__ h_tag){
  int idx = blockIdx.x*256 + threadIdx.x;     // 512 blocks -> 131072 = 2*B*H u64
  h_tag[idx] = 0ull;                          // val=0.0f, tag=0  (t=0 wants tag 0)
}

// ---------------- slot projections: Es/Eq = embed @ W_o.T (10 x 512) ----------------
__global__ void k_prep(const float* __restrict__ embed_s, const float* __restrict__ embed_q,
                       const float* __restrict__ w_s, const float* __restrict__ w_q,
                       float* __restrict__ es_proj, float* __restrict__ eq_proj){
  int bid = blockIdx.x;                 // 40 blocks
  int table = bid/20, rem = bid%20, s = rem/2, half = rem%2;
  int jo = half*256 + threadIdx.x;
  const float* emb = (table ? embed_q : embed_s) + s*D_;
  const float* w   = (table ? w_q : w_s) + (size_t)(2*H_ + jo)*D_;   // o-gate rows
  float acc = 0.f;
  #pragma unroll 4
  for (int k=0;k<D_;++k) acc = fmaf(emb[k], w[k], acc);
  (table ? eq_proj : es_proj)[s*H_ + jo] = acc;
}

// ---------------- phase 1: P[t][b][j], j<512 = g-gate preact, j>=512 = o-gate preact ----------------
__global__ __launch_bounds__(256) void k_phase1(
  const int* __restrict__ batch_l, const float* __restrict__ embed_l,
  const float* __restrict__ w_ih, const float* __restrict__ b_ih, const float* __restrict__ b_hh,
  const float* __restrict__ t_ld, const float* __restrict__ t_hd,
  const int* __restrict__ t_l, const int* __restrict__ t_h,
  const float* __restrict__ d_ld, const float* __restrict__ d_hd,
  const int* __restrict__ d_l, const int* __restrict__ d_h,
  const float* __restrict__ es_proj, const float* __restrict__ eq_proj,
  float* __restrict__ P)
{
  __shared__ float As[8][72];
  __shared__ float Bs[8][72];
  __shared__ int ridx[64];
  int mt = blockIdx.x, jt = blockIdx.y;       // 200 x 16
  int t = mt >> 1, b0 = (mt & 1)*64;
  int tid = threadIdx.x;
  if (tid < 64) ridx[tid] = batch_l[(b0+tid)*T_ + t];
  __syncthreads();
  int ty = tid >> 4, tx = tid & 15;
  int r_s = tid >> 2;
  int kk_s = (tid & 3)*2;
  const float* arow = embed_l + (size_t)ridx[r_s]*D_ + kk_s;
  const float* brow = w_ih + (size_t)(2*H_ + jt*64 + r_s)*D_ + kk_s;
  float acc[4][4] = {};
  for (int kc = 0; kc < 32; ++kc) {
    int k0 = kc*8;
    float2 av = *(const float2*)(arow + k0);
    float2 bv = *(const float2*)(brow + k0);
    __syncthreads();
    As[kk_s][r_s] = av.x; As[kk_s+1][r_s] = av.y;
    Bs[kk_s][r_s] = bv.x; Bs[kk_s+1][r_s] = bv.y;
    __syncthreads();
    #pragma unroll
    for (int kk=0;kk<8;++kk){
      float4 a4 = *(const float4*)&As[kk][ty*4];
      float4 b4 = *(const float4*)&Bs[kk][tx*4];
      float avv[4] = {a4.x,a4.y,a4.z,a4.w};
      float bvv[4] = {b4.x,b4.y,b4.z,b4.w};
      #pragma unroll
      for (int i=0;i<4;++i)
        #pragma unroll
        for (int j=0;j<4;++j) acc[i][j] = fmaf(avv[i], bvv[j], acc[i][j]);
    }
  }
  int j0 = jt*64 + tx*4;
  float bias[4];
  #pragma unroll
  for (int j=0;j<4;++j) bias[j] = b_ih[2*H_ + j0 + j] + b_hh[2*H_ + j0 + j];
  #pragma unroll
  for (int i=0;i<4;++i){
    int b = b0 + ty*4 + i;
    size_t m = (size_t)t*B_ + b;
    float add[4] = {0.f,0.f,0.f,0.f};
    if (jt >= 8) {
      int bt = b*T_ + t;
      float dld = d_ld[bt], dhd = d_hd[bt];
      float tld = t_ld[bt], thd = t_hd[bt];
      int dl = d_l[bt], dh = d_h[bt], tl = t_l[bt], th = t_h[bt];
      int jo = j0 - 512;
      #pragma unroll
      for (int j=0;j<4;++j)
        add[j] = dhd*es_proj[dl*H_+jo+j] + dld*es_proj[dh*H_+jo+j]
               + thd*eq_proj[tl*H_+jo+j] + tld*eq_proj[th*H_+jo+j];
    }
    float4 o4;
    o4.x = acc[i][0] + bias[0] + add[0];
    o4.y = acc[i][1] + bias[1] + add[1];
    o4.z = acc[i][2] + bias[2] + add[2];
    o4.w = acc[i][3] + bias[3] + add[3];
    *(float4*)&P[m*1024 + j0] = o4;
  }
}

// ---------------- recurrence: persistent, 256 WGs x 512 thr = 32 bg x 8 js ----------------
// Round-6: cut fabric read-amplification 4x. Grid = 32 batch-groups (4 batches) x 8
// j-slices (64 j each). Per-step uncached LLC reads: 8 js x 4b x 512 x 8B = 4MB (was 16MB).
// Whh weights fully in registers (w[8][16], 128 VGPR). h staged as float4 LDS tiles,
// ds_read_b128. Tag-in-data protocol (proof of safety as round 5: parity double buffer,
// max skew 1 step, tags advance +2 per slot so the ==t check cannot be skipped).
// Each thread polls ONLY its own 4 elements, reloading just the stale ones.
__global__ __launch_bounds__(512,1) void k_rec(
  const float* __restrict__ w_hh, const float* __restrict__ P,
  unsigned long long* __restrict__ h_tag)
{
  __shared__ float4 ht4[512];                     // ht4[k] = h[k][b0..b3] for this bg
  int bid = blockIdx.x;
  int bg = bid & 31;                              // 32 groups x 4 batches
  int js = bid >> 5;                              // 8 slices x 64 j
  int tid = threadIdx.x;
  int rq = tid >> 5;                              // 0..15 -> 4 j rows each
  int kq = tid & 31;                              // 0..31 -> k split
  int j0 = js*64 + rq*4;
  const float* Wg = w_hh + (size_t)2*H_*H_;       // g rows [0,512)
  const float* Wo = w_hh + (size_t)3*H_*H_;       // o rows [0,512)

  // ---- weights -> registers: rows 0..3 = g(j0+jj), 4..7 = o(j0+jj); k = kk*32+kq
  float w[8][16];
  #pragma unroll
  for (int jj=0;jj<4;++jj){
    const float* sg = Wg + (size_t)(j0+jj)*H_ + kq;
    const float* so = Wo + (size_t)(j0+jj)*H_ + kq;
    #pragma unroll
    for (int kk=0;kk<16;++kk){ w[jj][kk] = sg[kk*32]; w[4+jj][kk] = so[kk*32]; }
  }

  // ---- P prefetch for t=0 (active lanes kq<4 handle batch b=kq)
  float pgv[4] = {0,0,0,0}, pov[4] = {0,0,0,0};
  if (kq < 4){
    size_t prow = (size_t)(bg*4 + kq)*1024;
    float4 g4 = *(const float4*)&P[prow + j0];
    float4 o4 = *(const float4*)&P[prow + 512 + j0];
    pgv[0]=g4.x; pgv[1]=g4.y; pgv[2]=g4.z; pgv[3]=g4.w;
    pov[0]=o4.x; pov[1]=o4.y; pov[2]=o4.z; pov[3]=o4.w;
  }

  for (int t=0; t<T_; ++t){
    int par = t & 1;
    const unsigned long long* hsrc =
      h_tag + (size_t)par*(B_*H_) + (size_t)(bg*4)*H_ + tid;   // thread owns k=tid
    // ---- poll own 4 elements (tag must equal t), reload only stale
    VT v[4];
    #pragma unroll
    for (int b=0;b<4;++b)
      v[b].u = __hip_atomic_load(&hsrc[(size_t)b*H_], __ATOMIC_RELAXED, __HIP_MEMORY_SCOPE_AGENT);
    unsigned want = (unsigned)t;
    int guard = 0;
    while (true){
      int bad = 0;
      #pragma unroll
      for (int b=0;b<4;++b) bad |= (v[b].s.tag != want) ? (1<<b) : 0;
      if (!bad) break;
      if (++guard > (1<<20)) break;               // safety bail (never in normal operation)
      #pragma unroll
      for (int b=0;b<4;++b)
        if (bad & (1<<b))
          v[b].u = __hip_atomic_load(&hsrc[(size_t)b*H_], __ATOMIC_RELAXED, __HIP_MEMORY_SCOPE_AGENT);
    }
    ht4[tid] = make_float4(v[0].s.val, v[1].s.val, v[2].s.val, v[3].s.val);
    __syncthreads();

    // ---- compute: acc[r][b] = sum_k w[r][k]*h[k][b]
    float acc[8][4] = {};
    #pragma unroll
    for (int kk=0; kk<16; ++kk){
      float4 hv = ht4[kk*32 + kq];
      float hvv[4] = {hv.x, hv.y, hv.z, hv.w};
      #pragma unroll
      for (int r=0;r<8;++r)
        #pragma unroll
        for (int b=0;b<4;++b) acc[r][b] = fmaf(w[r][kk], hvv[b], acc[r][b]);
    }
    // ---- butterfly reduce over kq (all 32 lanes end with the sum)
    #pragma unroll
    for (int r=0;r<8;++r)
      #pragma unroll
      for (int b=0;b<4;++b){
        float s = acc[r][b];
        s += __shfl_xor(s, 1, 64);
        s += __shfl_xor(s, 2, 64);
        s += __shfl_xor(s, 4, 64);
        s += __shfl_xor(s, 8, 64);
        s += __shfl_xor(s, 16, 64);
        acc[r][b] = s;
      }
    // ---- epilogue: lane kq=b computes 4 h values for batch b, stores with tag t+1
    if (kq < 4){
      int b = kq;
      unsigned long long* dst =
        h_tag + (size_t)(1-par)*(B_*H_) + (size_t)(bg*4 + b)*H_ + j0;
      #pragma unroll
      for (int jj=0;jj<4;++jj){
        float gg = acc[jj][b]   + pgv[jj];
        float oo = acc[4+jj][b] + pov[jj];
        VT h2;
        h2.s.val = sigm_(oo)*tanh_(tanh_(gg));
        h2.s.tag = (unsigned)(t+1);
        __hip_atomic_store(&dst[jj], h2.u, __ATOMIC_RELAXED, __HIP_MEMORY_SCOPE_AGENT);
      }
      // prefetch next step's P while peers catch up
      if (t+1 < T_){
        size_t prow = ((size_t)(t+1)*B_ + bg*4 + b)*1024;
        float4 g4 = *(const float4*)&P[prow + j0];
        float4 o4 = *(const float4*)&P[prow + 512 + j0];
        pgv[0]=g4.x; pgv[1]=g4.y; pgv[2]=g4.z; pgv[3]=g4.w;
        pov[0]=o4.x; pov[1]=o4.y; pov[2]=o4.z; pov[3]=o4.w;
      }
    }
    __syncthreads();   // ht4 fully consumed before next iteration overwrites it
  }
}

// ---------------- classifier: out = hT @ w_out.T + b_out (hT = h_tag[buf 0] .val) ----------------
__global__ __launch_bounds__(256) void k_cls(
  const unsigned long long* __restrict__ h_tag, const float* __restrict__ w_out,
  const float* __restrict__ b_out, float* __restrict__ out)
{
  __shared__ float wt[32*68];     // [k][l] k-major
  __shared__ float htl[32*132];   // [k][b]
  const float* hTv = (const float*)h_tag;   // (val,tag) pairs; val at even float index
  int l0 = blockIdx.x * 64;       // 625 blocks
  int tid = threadIdx.x;
  int lq = tid >> 4, bq = tid & 15;
  float acc[4][8] = {};
  for (int kc=0; kc<16; ++kc){
    int k0 = kc*32;
    __syncthreads();
    for (int it=0; it<8; ++it){
      int e = it*256 + tid; int k = e & 31, l = e >> 5;
      wt[k*68 + l] = w_out[(size_t)(l0+l)*H_ + k0 + k];
    }
    for (int it=0; it<16; ++it){
      int e = it*256 + tid; int k = e & 31, b = e >> 5;
      htl[k*132 + b] = hTv[(size_t)(b*H_ + k0 + k)*2];
    }
    __syncthreads();
    #pragma unroll 4
    for (int k=0;k<32;++k){
      float4 w4 = *(const float4*)&wt[k*68 + lq*4];
      float4 h0 = *(const float4*)&htl[k*132 + bq*8];
      float4 h1 = *(const float4*)&htl[k*132 + bq*8 + 4];
      float wv[4] = {w4.x,w4.y,w4.z,w4.w};
      float hv[8] = {h0.x,h0.y,h0.z,h0.w,h1.x,h1.y,h1.z,h1.w};
      #pragma unroll
      for (int m=0;m<4;++m)
        #pragma unroll
        for (int i=0;i<8;++i) acc[m][i] = fmaf(wv[m], hv[i], acc[m][i]);
    }
  }
  int l = l0 + lq*4;
  float4 bo = *(const float4*)&b_out[l];
  #pragma unroll
  for (int i=0;i<8;++i){
    int b = bq*8 + i;
    float4 o4;
    o4.x = acc[0][i] + bo.x; o4.y = acc[1][i] + bo.y;
    o4.z = acc[2][i] + bo.z; o4.w = acc[3][i] + bo.w;
    *(float4*)&out[(size_t)b*L_ + l] = o4;
  }
}

extern "C" void kernel_launch(void* const* d_in, const int* in_sizes, int n_in,
                              void* d_out, int out_size, void* d_ws, size_t ws_size,
                              hipStream_t stream) {
  const int*   batch_l = (const int*)  d_in[0];
  const float* t_ld    = (const float*)d_in[1];
  const float* t_hd    = (const float*)d_in[2];
  const int*   t_l     = (const int*)  d_in[3];
  const int*   t_h     = (const int*)  d_in[4];
  const float* d_ld    = (const float*)d_in[5];
  const float* d_hd    = (const float*)d_in[6];
  const int*   d_l     = (const int*)  d_in[7];
  const int*   d_h     = (const int*)  d_in[8];
  const float* embed_l = (const float*)d_in[9];
  const float* embed_s = (const float*)d_in[10];
  const float* embed_q = (const float*)d_in[11];
  const float* w_ih    = (const float*)d_in[12];
  const float* w_hh    = (const float*)d_in[13];
  const float* w_s     = (const float*)d_in[14];
  const float* w_q     = (const float*)d_in[15];
  const float* b_ih    = (const float*)d_in[16];
  const float* b_hh    = (const float*)d_in[17];
  const float* w_out   = (const float*)d_in[18];
  const float* b_out   = (const float*)d_in[19];
  float* out = (float*)d_out;

  // workspace layout (float offsets; h_tag is u64 and 8B-aligned since offset is even)
  float* ws = (float*)d_ws;
  const size_t P_off  = 0;                          // 100*128*1024 = 13107200 f
  const size_t h_off  = 13107200;                   // 2*B*H u64 = 131072 u64 = 262144 f
  const size_t es_off = h_off + 262144;             // 5120 f
  const size_t eq_off = es_off + 5120;              // 5120 f
  const size_t need_bytes = (eq_off + 5120)*4 + 64;
  if (ws_size < need_bytes) return;

  float* P        = ws + P_off;
  unsigned long long* h_tag = (unsigned long long*)(ws + h_off);
  float* es_proj  = ws + es_off;
  float* eq_proj  = ws + eq_off;

  k_zero<<<512, 256, 0, stream>>>(h_tag);
  k_prep<<<40, 256, 0, stream>>>(embed_s, embed_q, w_s, w_q, es_proj, eq_proj);
  k_phase1<<<dim3(200,16), 256, 0, stream>>>(batch_l, embed_l, w_ih, b_ih, b_hh,
      t_ld, t_hd, t_l, t_h, d_ld, d_hd, d_l, d_h, es_proj, eq_proj, P);
  k_rec<<<256, 512, 0, stream>>>(w_hh, P, h_tag);
  k_cls<<<625, 256, 0, stream>>>(h_tag, w_out, b_out, out);
}

// Round 7
// 1543.670 us; speedup vs baseline: 3.0753x; 3.0753x over previous
//
#include <hip/hip_runtime.h>

#define B_ 128
#define T_ 100
#define D_ 256
#define H_ 512
#define L_ 40000
#define S_ 10

__device__ __forceinline__ float sigm_(float x){ return 1.f/(1.f + __expf(-x)); }
__device__ __forceinline__ float tanh_(float x){ return 1.f - 2.f/(__expf(2.f*x) + 1.f); }

// h exchange element: low 32 = value, high 32 = step tag. 8B atomic => no tearing.
union VT { struct { float val; unsigned tag; } s; unsigned long long u; };

// ---------------- zero h tag-buffer (both parities) ----------------
__global__ void k_zero(unsigned long long* __restrict__ h_tag){
  int idx = blockIdx.x*256 + threadIdx.x;     // 512 blocks -> 131072 = 2*B*H u64
  h_tag[idx] = 0ull;                          // val=0.0f, tag=0  (t=0 wants tag 0)
}

// ---------------- slot projections: Es/Eq = embed @ W_o.T (10 x 512) ----------------
__global__ void k_prep(const float* __restrict__ embed_s, const float* __restrict__ embed_q,
                       const float* __restrict__ w_s, const float* __restrict__ w_q,
                       float* __restrict__ es_proj, float* __restrict__ eq_proj){
  int bid = blockIdx.x;                 // 40 blocks
  int table = bid/20, rem = bid%20, s = rem/2, half = rem%2;
  int jo = half*256 + threadIdx.x;
  const float* emb = (table ? embed_q : embed_s) + s*D_;
  const float* w   = (table ? w_q : w_s) + (size_t)(2*H_ + jo)*D_;   // o-gate rows
  float acc = 0.f;
  #pragma unroll 4
  for (int k=0;k<D_;++k) acc = fmaf(emb[k], w[k], acc);
  (table ? eq_proj : es_proj)[s*H_ + jo] = acc;
}

// ---------------- phase 1: P[t][b][j], j<512 = g-gate preact, j>=512 = o-gate preact ----------------
__global__ __launch_bounds__(256) void k_phase1(
  const int* __restrict__ batch_l, const float* __restrict__ embed_l,
  const float* __restrict__ w_ih, const float* __restrict__ b_ih, const float* __restrict__ b_hh,
  const float* __restrict__ t_ld, const float* __restrict__ t_hd,
  const int* __restrict__ t_l, const int* __restrict__ t_h,
  const float* __restrict__ d_ld, const float* __restrict__ d_hd,
  const int* __restrict__ d_l, const int* __restrict__ d_h,
  const float* __restrict__ es_proj, const float* __restrict__ eq_proj,
  float* __restrict__ P)
{
  __shared__ float As[8][72];
  __shared__ float Bs[8][72];
  __shared__ int ridx[64];
  int mt = blockIdx.x, jt = blockIdx.y;       // 200 x 16
  int t = mt >> 1, b0 = (mt & 1)*64;
  int tid = threadIdx.x;
  if (tid < 64) ridx[tid] = batch_l[(b0+tid)*T_ + t];
  __syncthreads();
  int ty = tid >> 4, tx = tid & 15;
  int r_s = tid >> 2;
  int kk_s = (tid & 3)*2;
  const float* arow = embed_l + (size_t)ridx[r_s]*D_ + kk_s;
  const float* brow = w_ih + (size_t)(2*H_ + jt*64 + r_s)*D_ + kk_s;
  float acc[4][4] = {};
  for (int kc = 0; kc < 32; ++kc) {
    int k0 = kc*8;
    float2 av = *(const float2*)(arow + k0);
    float2 bv = *(const float2*)(brow + k0);
    __syncthreads();
    As[kk_s][r_s] = av.x; As[kk_s+1][r_s] = av.y;
    Bs[kk_s][r_s] = bv.x; Bs[kk_s+1][r_s] = bv.y;
    __syncthreads();
    #pragma unroll
    for (int kk=0;kk<8;++kk){
      float4 a4 = *(const float4*)&As[kk][ty*4];
      float4 b4 = *(const float4*)&Bs[kk][tx*4];
      float avv[4] = {a4.x,a4.y,a4.z,a4.w};
      float bvv[4] = {b4.x,b4.y,b4.z,b4.w};
      #pragma unroll
      for (int i=0;i<4;++i)
        #pragma unroll
        for (int j=0;j<4;++j) acc[i][j] = fmaf(avv[i], bvv[j], acc[i][j]);
    }
  }
  int j0 = jt*64 + tx*4;
  float bias[4];
  #pragma unroll
  for (int j=0;j<4;++j) bias[j] = b_ih[2*H_ + j0 + j] + b_hh[2*H_ + j0 + j];
  #pragma unroll
  for (int i=0;i<4;++i){
    int b = b0 + ty*4 + i;
    size_t m = (size_t)t*B_ + b;
    float add[4] = {0.f,0.f,0.f,0.f};
    if (jt >= 8) {
      int bt = b*T_ + t;
      float dld = d_ld[bt], dhd = d_hd[bt];
      float tld = t_ld[bt], thd = t_hd[bt];
      int dl = d_l[bt], dh = d_h[bt], tl = t_l[bt], th = t_h[bt];
      int jo = j0 - 512;
      #pragma unroll
      for (int j=0;j<4;++j)
        add[j] = dhd*es_proj[dl*H_+jo+j] + dld*es_proj[dh*H_+jo+j]
               + thd*eq_proj[tl*H_+jo+j] + tld*eq_proj[th*H_+jo+j];
    }
    float4 o4;
    o4.x = acc[i][0] + bias[0] + add[0];
    o4.y = acc[i][1] + bias[1] + add[1];
    o4.z = acc[i][2] + bias[2] + add[2];
    o4.w = acc[i][3] + bias[3] + add[3];
    *(float4*)&P[m*1024 + j0] = o4;
  }
}

// ---------------- recurrence: persistent, 512 WGs x 512 thr = 32 bg x 16 js ----------------
// Round-7: fix r6's register-spill catastrophe (w[8][16]=128 regs => scratch => 7.7GB
// writes). Same tag-in-data protocol; now w[4][16]=64 regs/thread (est ~110 VGPR, cap 128
// via __launch_bounds__(512,4)), and 2 WGs/CU from DIFFERENT batch-groups (bg = bid>>4:
// blocks c and c+256 share a CU under round-robin dispatch but belong to different,
// fully independent chains) so one chain computes while the other waits on sync.
// Safety of tag protocol (unchanged): parity double buffer; every bg-WG reads ALL 512 k
// of its 4 batches each step, so a writer can only reach step t+2 (overwriting tag-t
// slots) after every peer consumed its tag-t data; tags per slot advance by exactly +2
// per parity so the ==t check cannot be skipped past.
__global__ __launch_bounds__(512,4) void k_rec(
  const float* __restrict__ w_hh, const float* __restrict__ P,
  unsigned long long* __restrict__ h_tag)
{
  __shared__ float4 ht4[512];                     // ht4[k] = h[k][b0..b3] for this bg
  int bid = blockIdx.x;
  int bg = bid >> 4;                              // 0..31: 4 batches each
  int js = bid & 15;                              // 0..15: 32 j-cols each
  int tid = threadIdx.x;
  int rq = tid >> 5;                              // 0..15 -> j-pair
  int kq = tid & 31;                              // 0..31 -> k split
  int j0 = js*32 + rq*2;
  const float* Wg = w_hh + (size_t)2*H_*H_;       // g rows [0,512)
  const float* Wo = w_hh + (size_t)3*H_*H_;       // o rows [0,512)

  // ---- weights -> registers: w[0..1]=g(j0,j0+1), w[2..3]=o(j0,j0+1); k = kk*32+kq
  float w[4][16];
  #pragma unroll
  for (int jj=0;jj<2;++jj){
    const float* sg = Wg + (size_t)(j0+jj)*H_ + kq;
    const float* so = Wo + (size_t)(j0+jj)*H_ + kq;
    #pragma unroll
    for (int kk=0;kk<16;++kk){ w[jj][kk] = sg[kk*32]; w[2+jj][kk] = so[kk*32]; }
  }

  // ---- P prefetch for t=0 (lane kq<4 owns batch b=kq)
  float2 pg = {0.f,0.f}, po = {0.f,0.f};
  if (kq < 4){
    size_t prow = (size_t)(bg*4 + kq)*1024;
    pg = *(const float2*)&P[prow + j0];
    po = *(const float2*)&P[prow + 512 + j0];
  }

  for (int t=0; t<T_; ++t){
    int par = t & 1;
    const unsigned long long* hsrc =
      h_tag + (size_t)par*(B_*H_) + (size_t)(bg*4)*H_ + tid;   // thread owns k=tid
    // ---- poll own 4 elements (tag must equal t), reload only stale
    VT v[4];
    #pragma unroll
    for (int b=0;b<4;++b)
      v[b].u = __hip_atomic_load(&hsrc[(size_t)b*H_], __ATOMIC_RELAXED, __HIP_MEMORY_SCOPE_AGENT);
    unsigned want = (unsigned)t;
    int guard = 0;
    while (true){
      int bad = 0;
      #pragma unroll
      for (int b=0;b<4;++b) bad |= (v[b].s.tag != want) ? (1<<b) : 0;
      if (!bad) break;
      if (++guard > (1<<20)) break;               // safety bail (never in normal operation)
      #pragma unroll
      for (int b=0;b<4;++b)
        if (bad & (1<<b))
          v[b].u = __hip_atomic_load(&hsrc[(size_t)b*H_], __ATOMIC_RELAXED, __HIP_MEMORY_SCOPE_AGENT);
    }
    ht4[tid] = make_float4(v[0].s.val, v[1].s.val, v[2].s.val, v[3].s.val);
    __syncthreads();

    // ---- compute: acc[r][b] = sum over own k-slice of w[r][k]*h[k][b]
    float acc[4][4] = {};
    #pragma unroll
    for (int kk=0; kk<16; ++kk){
      float4 hv = ht4[kk*32 + kq];
      float hvv[4] = {hv.x, hv.y, hv.z, hv.w};
      #pragma unroll
      for (int r=0;r<4;++r)
        #pragma unroll
        for (int b=0;b<4;++b) acc[r][b] = fmaf(w[r][kk], hvv[b], acc[r][b]);
    }
    // ---- butterfly reduce over kq (lane = (rq&1)*32 + kq; xor<=16 stays in kq group)
    #pragma unroll
    for (int r=0;r<4;++r)
      #pragma unroll
      for (int b=0;b<4;++b){
        float s = acc[r][b];
        s += __shfl_xor(s, 1, 64);
        s += __shfl_xor(s, 2, 64);
        s += __shfl_xor(s, 4, 64);
        s += __shfl_xor(s, 8, 64);
        s += __shfl_xor(s, 16, 64);
        acc[r][b] = s;
      }
    // ---- epilogue: lane kq=b computes h(j0), h(j0+1) for batch b, stores with tag t+1
    if (kq < 4){
      int b = kq;
      unsigned long long* dst =
        h_tag + (size_t)(1-par)*(B_*H_) + (size_t)(bg*4 + b)*H_ + j0;
      #pragma unroll
      for (int jj=0;jj<2;++jj){
        float gg = acc[jj][b]   + ((jj==0)? pg.x : pg.y);
        float oo = acc[2+jj][b] + ((jj==0)? po.x : po.y);
        VT h2;
        h2.s.val = sigm_(oo)*tanh_(tanh_(gg));
        h2.s.tag = (unsigned)(t+1);
        __hip_atomic_store(&dst[jj], h2.u, __ATOMIC_RELAXED, __HIP_MEMORY_SCOPE_AGENT);
      }
      // prefetch next step's P while peers catch up
      if (t+1 < T_){
        size_t prow = ((size_t)(t+1)*B_ + bg*4 + b)*1024;
        pg = *(const float2*)&P[prow + j0];
        po = *(const float2*)&P[prow + 512 + j0];
      }
    }
    __syncthreads();   // ht4 fully consumed before next iteration overwrites it
  }
}

// ---------------- classifier: out = hT @ w_out.T + b_out (hT = h_tag[buf 0] .val) ----------------
__global__ __launch_bounds__(256) void k_cls(
  const unsigned long long* __restrict__ h_tag, const float* __restrict__ w_out,
  const float* __restrict__ b_out, float* __restrict__ out)
{
  __shared__ float wt[32*68];     // [k][l] k-major
  __shared__ float htl[32*132];   // [k][b]
  const float* hTv = (const float*)h_tag;   // (val,tag) pairs; val at even float index
  int l0 = blockIdx.x * 64;       // 625 blocks
  int tid = threadIdx.x;
  int lq = tid >> 4, bq = tid & 15;
  float acc[4][8] = {};
  for (int kc=0; kc<16; ++kc){
    int k0 = kc*32;
    __syncthreads();
    for (int it=0; it<8; ++it){
      int e = it*256 + tid; int k = e & 31, l = e >> 5;
      wt[k*68 + l] = w_out[(size_t)(l0+l)*H_ + k0 + k];
    }
    for (int it=0; it<16; ++it){
      int e = it*256 + tid; int k = e & 31, b = e >> 5;
      htl[k*132 + b] = hTv[(size_t)(b*H_ + k0 + k)*2];
    }
    __syncthreads();
    #pragma unroll 4
    for (int k=0;k<32;++k){
      float4 w4 = *(const float4*)&wt[k*68 + lq*4];
      float4 h0 = *(const float4*)&htl[k*132 + bq*8];
      float4 h1 = *(const float4*)&htl[k*132 + bq*8 + 4];
      float wv[4] = {w4.x,w4.y,w4.z,w4.w};
      float hv[8] = {h0.x,h0.y,h0.z,h0.w,h1.x,h1.y,h1.z,h1.w};
      #pragma unroll
      for (int m=0;m<4;++m)
        #pragma unroll
        for (int i=0;i<8;++i) acc[m][i] = fmaf(wv[m], hv[i], acc[m][i]);
    }
  }
  int l = l0 + lq*4;
  float4 bo = *(const float4*)&b_out[l];
  #pragma unroll
  for (int i=0;i<8;++i){
    int b = bq*8 + i;
    float4 o4;
    o4.x = acc[0][i] + bo.x; o4.y = acc[1][i] + bo.y;
    o4.z = acc[2][i] + bo.z; o4.w = acc[3][i] + bo.w;
    *(float4*)&out[(size_t)b*L_ + l] = o4;
  }
}

extern "C" void kernel_launch(void* const* d_in, const int* in_sizes, int n_in,
                              void* d_out, int out_size, void* d_ws, size_t ws_size,
                              hipStream_t stream) {
  const int*   batch_l = (const int*)  d_in[0];
  const float* t_ld    = (const float*)d_in[1];
  const float* t_hd    = (const float*)d_in[2];
  const int*   t_l     = (const int*)  d_in[3];
  const int*   t_h     = (const int*)  d_in[4];
  const float* d_ld    = (const float*)d_in[5];
  const float* d_hd    = (const float*)d_in[6];
  const int*   d_l     = (const int*)  d_in[7];
  const int*   d_h     = (const int*)  d_in[8];
  const float* embed_l = (const float*)d_in[9];
  const float* embed_s = (const float*)d_in[10];
  const float* embed_q = (const float*)d_in[11];
  const float* w_ih    = (const float*)d_in[12];
  const float* w_hh    = (const float*)d_in[13];
  const float* w_s     = (const float*)d_in[14];
  const float* w_q     = (const float*)d_in[15];
  const float* b_ih    = (const float*)d_in[16];
  const float* b_hh    = (const float*)d_in[17];
  const float* w_out   = (const float*)d_in[18];
  const float* b_out   = (const float*)d_in[19];
  float* out = (float*)d_out;

  // workspace layout (float offsets; h_tag is u64 and 8B-aligned since offset is even)
  float* ws = (float*)d_ws;
  const size_t P_off  = 0;                          // 100*128*1024 = 13107200 f
  const size_t h_off  = 13107200;                   // 2*B*H u64 = 131072 u64 = 262144 f
  const size_t es_off = h_off + 262144;             // 5120 f
  const size_t eq_off = es_off + 5120;              // 5120 f
  const size_t need_bytes = (eq_off + 5120)*4 + 64;
  if (ws_size < need_bytes) return;

  float* P        = ws + P_off;
  unsigned long long* h_tag = (unsigned long long*)(ws + h_off);
  float* es_proj  = ws + es_off;
  float* eq_proj  = ws + eq_off;

  k_zero<<<512, 256, 0, stream>>>(h_tag);
  k_prep<<<40, 256, 0, stream>>>(embed_s, embed_q, w_s, w_q, es_proj, eq_proj);
  k_phase1<<<dim3(200,16), 256, 0, stream>>>(batch_l, embed_l, w_ih, b_ih, b_hh,
      t_ld, t_hd, t_l, t_h, d_ld, d_hd, d_l, d_h, es_proj, eq_proj, P);
  k_rec<<<512, 512, 0, stream>>>(w_hh, P, h_tag);
  k_cls<<<625, 256, 0, stream>>>(h_tag, w_out, b_out, out);
}